// Round 10
// baseline (47.722 us; speedup 1.0000x reference)
//
#include <hip/hip_runtime.h>

#define B_     8
#define L_     512
#define DIM_   256
#define INNER_ 512
#define M_ROWS (B_*L_)        // 4096

typedef __bf16 bf16x8 __attribute__((ext_vector_type(8)));
typedef float  fl4    __attribute__((ext_vector_type(4)));

typedef const __attribute__((address_space(1))) void gvoid;
typedef __attribute__((address_space(3))) void lvoid;

__device__ __forceinline__ void gl_lds16(const void* g, void* l) {
    __builtin_amdgcn_global_load_lds((gvoid*)g, (lvoid*)l, 16, 0, 0);
}
__device__ __forceinline__ unsigned short f2bf(float f) {
    unsigned int u = __float_as_uint(f);
    u = (u + 0x7fffu + ((u >> 16) & 1u)) >> 16;   // RNE
    return (unsigned short)u;
}
__device__ __forceinline__ ushort4 f4bf4(float4 v) {
    union { __bf16 h[4]; ushort4 u; } r;
    r.h[0] = (__bf16)v.x; r.h[1] = (__bf16)v.y;
    r.h[2] = (__bf16)v.z; r.h[3] = (__bf16)v.w;
    return r.u;
}

// Swizzle convention for yb and woutb (both [row][512] bf16, produced by us,
// consumed only by p3): logical element (row, c) is stored at
// phys col = c ^ ((row & 7) << 3)   (16-byte granule XOR within 128B window).
// p3 stages tiles with global_load_lds LINEARLY (copy is layout-agnostic) and
// applies the same XOR on its LDS fragment reads -> 2-way banks (free).

// ---------------------------------------------------------------- K1: gemm1 + conv + scan + gate
// HEAD (blocks 0..63): convert Wout f32 -> bf16 pre-swizzled + __threadfence
// release, so the stores are device-visible long before this kernel ends.
// Then: exact round-9 passing body (GEMM staged f32->bf16 into padded LDS,
// conv(3) + scan + gate, swizzled yb store).
__global__ __launch_bounds__(512) void p1_fused(
    const float* __restrict__ x, const float* __restrict__ Win,
    const float* __restrict__ convw, const float* __restrict__ sdecay,
    const float* __restrict__ sscale,
    const float* __restrict__ wout, unsigned short* __restrict__ woutb,
    unsigned short* __restrict__ yb)
{
    constexpr int BK = 64;
    constexpr int LDA = BK + 8;      // 72 bf16, stride 144 B
    __shared__ __align__(16) char smem[80*1024];
    unsigned short* As = (unsigned short*)smem;            // [512][72] bf16 = 73728 B
    unsigned short* Bs = (unsigned short*)(smem + 73728);  // [32][72]  bf16 = 4608 B
    float* u_lds = (float*)smem;                           // [512][17] f32 = 34816 B
    float* g_lds = (float*)(smem + 34816);                 // [512][17]
    float* carry = (float*)(smem + 69632);                 // [32][16]

    const int tid  = threadIdx.x;
    const int wave = tid >> 6, lane = tid & 63;
    const int b  = blockIdx.x >> 5;
    const int cg = blockIdx.x & 31;

    // ---- head: Wout convert (32768 float4s over blocks 0..63) ----
    if (blockIdx.x < 64) {
        const int i4 = blockIdx.x * 512 + tid;   // 0..32767
        const int row = i4 >> 7;                 // 128 float4 per 512-elem row
        const int col = (i4 & 127) * 4;
        float4 v = *(const float4*)&wout[(size_t)i4*4];
        const int dcol = col ^ ((row & 7) << 3); // stays within [0,512), 4-aligned
        *(ushort4*)&woutb[(size_t)row*INNER_ + dcol] = f4bf4(v);
        __threadfence();                         // release stores device-wide early
    }

    fl4 acc[4][2] = {};   // wave rows: wave*64 + m*16..; cols: n=0 -> u, n=1 -> g

    const int kc = (tid & 15) * 4;       // col offset (f32 elems) this thread stages
    const int rsub = tid >> 4;           // 0..31

    for (int kt = 0; kt < DIM_; kt += BK) {
        __syncthreads();
        // stage A: 512 rows x 64 k (f32 -> bf16). thread: rows rsub + p*32, cols kc..kc+3
        #pragma unroll
        for (int p = 0; p < 16; ++p) {
            const int l = p*32 + rsub;
            float4 v = *(const float4*)&x[(size_t)(b*L_ + l)*DIM_ + kt + kc];
            *(ushort4*)&As[l*LDA + kc] = f4bf4(v);
        }
        // stage Win rows (32 x 64): thread rsub = Bs row, cols kc
        {
            const int wrow = (rsub < 16) ? (cg*16 + rsub) : (INNER_ + cg*16 + (rsub-16));
            float4 v = *(const float4*)&Win[(size_t)wrow*DIM_ + kt + kc];
            *(ushort4*)&Bs[rsub*LDA + kc] = f4bf4(v);
        }
        __syncthreads();

        #pragma unroll
        for (int kh = 0; kh < 2; ++kh) {
            bf16x8 af[4], bfr[2];
            #pragma unroll
            for (int m = 0; m < 4; ++m)
                af[m] = *(const bf16x8*)&As[(wave*64 + m*16 + (lane & 15))*LDA + kh*32 + (lane >> 4)*8];
            #pragma unroll
            for (int n = 0; n < 2; ++n)
                bfr[n] = *(const bf16x8*)&Bs[(n*16 + (lane & 15))*LDA + kh*32 + (lane >> 4)*8];
            #pragma unroll
            for (int m = 0; m < 4; ++m)
                #pragma unroll
                for (int n = 0; n < 2; ++n)
                    acc[m][n] = __builtin_amdgcn_mfma_f32_16x16x32_bf16(af[m], bfr[n], acc[m][n], 0, 0, 0);
        }
    }

    __syncthreads();          // all frag reads done; reuse LDS for scan
    #pragma unroll
    for (int m = 0; m < 4; ++m)
        #pragma unroll
        for (int r = 0; r < 4; ++r) {
            const int l = wave*64 + m*16 + (lane >> 4)*4 + r;
            const int c2 = lane & 15;
            u_lds[l*17 + c2] = acc[m][0][r];
            g_lds[l*17 + c2] = acc[m][1][r];
        }
    __syncthreads();

    // scan: thread = channel c2 (0..15) x chunk j (0..31) of 16 steps
    {
        const int c2 = tid & 15;
        const int j  = tid >> 4;
        const int c  = cg*16 + c2;                 // global channel

        const float draw = 1.0f / (1.0f + __expf(-sdecay[c]));
        const float deff = fmaxf(draw, 1e-6f);
        const float ins  = (1.0f - draw) * sscale[c];
        const float w0 = convw[c*3+0], w1 = convw[c*3+1], w2 = convw[c*3+2];

        const int l0 = j*16;
        float um1 = (l0 >= 1) ? u_lds[(l0-1)*17 + c2] : 0.f;
        float um2 = (l0 >= 2) ? u_lds[(l0-2)*17 + c2] : 0.f;

        float sloc[16];
        float s = 0.f;
        #pragma unroll
        for (int i = 0; i < 16; ++i) {
            const float u = u_lds[(l0+i)*17 + c2];
            const float uc = fmaf(w2, u, fmaf(w1, um1, w0*um2));
            um2 = um1; um1 = u;
            s = fmaf(deff, s, ins*uc);
            sloc[i] = s;
        }
        carry[j*16 + c2] = s;
        __syncthreads();
        const float dp16 = __powf(deff, 16.0f);
        float s0 = 0.f;
        for (int i = 0; i < j; ++i) s0 = fmaf(s0, dp16, carry[i*16 + c2]);

        float pw = 1.0f;
        #pragma unroll
        for (int i = 0; i < 16; ++i) {
            pw *= deff;
            const float sv   = fmaf(s0, pw, sloc[i]);
            const float gate = 1.0f / (1.0f + __expf(-g_lds[(l0+i)*17 + c2]));
            // swizzled store: l = l0+i, (l&7) == (i&7) since l0 is a multiple of 16
            yb[(size_t)(b*L_ + l0 + i)*INNER_ + (c ^ ((i & 7) << 3))] = f2bf(sv * gate);
        }
    }
}

// ---------------------------------------------------------------- K2: gemm2 + fused RMSNorm
// 256 blocks x 16 rows; full 256 output cols per block; K = 512, BK = 64.
// Staging is a linear copy of the pre-swizzled buffers; fragment reads apply
// the XOR -> conflict-free. (Byte-identical to round 9.)
__global__ __launch_bounds__(512) void p3_gemm2(
    const unsigned short* __restrict__ yb,
    const unsigned short* __restrict__ woutb,
    const float* __restrict__ normw,
    float* __restrict__ out)
{
    __shared__ __align__(16) char smem[36*1024];
    unsigned short* As2 = (unsigned short*)smem;          // [16][64]
    unsigned short* Bs2 = (unsigned short*)(smem + 2048); // [256][64]
    float* ssp = (float*)(smem + 2048 + 32768);           // [16][8]
    const int tid  = threadIdx.x;
    const int wave = tid >> 6, lane = tid & 63;
    const int r15 = lane & 15, q = lane >> 4;
    const int row0 = blockIdx.x * 16;
    const int wc   = wave * 32;
    const int sa   = (r15 & 7) << 3;                      // read-side swizzle
    fl4 acc[2] = {};
    for (int kt = 0; kt < INNER_; kt += 64) {
        __syncthreads();
        for (int ch = wave; ch < 34; ch += 8) {
            const int ke = (lane & 7) * 8;
            if (ch < 2)
                gl_lds16(yb    + (size_t)(row0 + ch*8 + (lane >> 3))*INNER_ + kt + ke,
                         (char*)As2 + ch*1024);
            else
                gl_lds16(woutb + (size_t)((ch-2)*8 + (lane >> 3))*INNER_ + kt + ke,
                         (char*)Bs2 + (ch-2)*1024);
        }
        __syncthreads();
        #pragma unroll
        for (int kh = 0; kh < 2; ++kh) {
            bf16x8 a = *(const bf16x8*)&As2[r15*64 + ((kh*32 + q*8) ^ sa)];
            #pragma unroll
            for (int n = 0; n < 2; ++n) {
                bf16x8 b = *(const bf16x8*)&Bs2[(wc + n*16 + r15)*64 + ((kh*32 + q*8) ^ sa)];
                acc[n] = __builtin_amdgcn_mfma_f32_16x16x32_bf16(a, b, acc[n], 0, 0, 0);
            }
        }
    }
    float t[4];
    #pragma unroll
    for (int qq = 0; qq < 4; ++qq) {
        float s = 0.f;
        #pragma unroll
        for (int n = 0; n < 2; ++n) { const float v = acc[n][qq]; s = fmaf(v, v, s); }
        s += __shfl_xor(s, 1, 64); s += __shfl_xor(s, 2, 64);
        s += __shfl_xor(s, 4, 64); s += __shfl_xor(s, 8, 64);
        t[qq] = s;
    }
    if (r15 == 0) {
        #pragma unroll
        for (int qq = 0; qq < 4; ++qq)
            ssp[(q*4 + qq)*8 + wave] = t[qq];
    }
    __syncthreads();
    #pragma unroll
    for (int qq = 0; qq < 4; ++qq) {
        const int rl = q*4 + qq;
        float ss = 0.f;
        #pragma unroll
        for (int w = 0; w < 8; ++w) ss += ssp[rl*8 + w];
        const float rf = rsqrtf(ss * (1.0f/DIM_) + 1e-6f);
        #pragma unroll
        for (int n = 0; n < 2; ++n) {
            const int col = wc + n*16 + r15;
            out[(size_t)(row0 + rl)*DIM_ + col] = acc[n][qq] * rf * normw[col];
        }
    }
}

// ---------------------------------------------------------------- launch
extern "C" void kernel_launch(void* const* d_in, const int* in_sizes, int n_in,
                              void* d_out, int out_size, void* d_ws, size_t ws_size,
                              hipStream_t stream)
{
    const float* x      = (const float*)d_in[0];
    const float* Win    = (const float*)d_in[1];
    const float* convw  = (const float*)d_in[2];
    const float* sdecay = (const float*)d_in[3];
    const float* sscale = (const float*)d_in[4];
    const float* Wout   = (const float*)d_in[5];
    const float* normw  = (const float*)d_in[6];
    float* out = (float*)d_out;

    char* ws = (char*)d_ws;
    unsigned short* woutb = (unsigned short*)(ws);            // 0.25 MB
    unsigned short* yb    = (unsigned short*)(ws + (1u<<20)); // 4 MB

    p1_fused<<<256, 512, 0, stream>>>(x, Win, convw, sdecay, sscale, Wout, woutb, yb);
    p3_gemm2<<<256, 512, 0, stream>>>(yb, woutb, normw, out);
}

// Round 11
// 30.844 us; speedup vs baseline: 1.5472x; 1.5472x over previous
//
#include <hip/hip_runtime.h>

#define B_     8
#define L_     512
#define DIM_   256
#define INNER_ 512
#define M_ROWS (B_*L_)        // 4096

typedef __bf16 bf16x8 __attribute__((ext_vector_type(8)));
typedef float  fl4    __attribute__((ext_vector_type(4)));

typedef const __attribute__((address_space(1))) void gvoid;
typedef __attribute__((address_space(3))) void lvoid;

__device__ __forceinline__ void gl_lds16(const void* g, void* l) {
    __builtin_amdgcn_global_load_lds((gvoid*)g, (lvoid*)l, 16, 0, 0);
}
__device__ __forceinline__ unsigned short f2bf(float f) {
    unsigned int u = __float_as_uint(f);
    u = (u + 0x7fffu + ((u >> 16) & 1u)) >> 16;   // RNE
    return (unsigned short)u;
}
__device__ __forceinline__ ushort4 f4bf4(float4 v) {
    union { __bf16 h[4]; ushort4 u; } r;
    r.h[0] = (__bf16)v.x; r.h[1] = (__bf16)v.y;
    r.h[2] = (__bf16)v.z; r.h[3] = (__bf16)v.w;
    return r.u;
}

// Swizzle convention for yb and woutb (both [row][512] bf16, produced by us,
// consumed only by p3): logical element (row, c) is stored at
// phys col = c ^ ((row & 7) << 3)   (16-byte granule XOR within 128B window).
// p3 stages tiles with global_load_lds LINEARLY (copy is layout-agnostic) and
// applies the same XOR on its LDS fragment reads -> 2-way banks (free).

// ---------------------------------------------------------------- K1: gemm1 + conv + scan + gate
// HEAD (tid<128, all 256 blocks): convert Wout f32 -> bf16 pre-swizzled.
// One 16B store per participating lane; NO fence (r10 showed __threadfence's
// L2 writeback-invalidate costs ~12us; r9 proved cross-node visibility works).
// Then: exact round-9 passing body.
__global__ __launch_bounds__(512) void p1_fused(
    const float* __restrict__ x, const float* __restrict__ Win,
    const float* __restrict__ convw, const float* __restrict__ sdecay,
    const float* __restrict__ sscale,
    const float* __restrict__ wout, unsigned short* __restrict__ woutb,
    unsigned short* __restrict__ yb)
{
    constexpr int BK = 64;
    constexpr int LDA = BK + 8;      // 72 bf16, stride 144 B
    __shared__ __align__(16) char smem[80*1024];
    unsigned short* As = (unsigned short*)smem;            // [512][72] bf16 = 73728 B
    unsigned short* Bs = (unsigned short*)(smem + 73728);  // [32][72]  bf16 = 4608 B
    float* u_lds = (float*)smem;                           // [512][17] f32 = 34816 B
    float* g_lds = (float*)(smem + 34816);                 // [512][17]
    float* carry = (float*)(smem + 69632);                 // [32][16]

    const int tid  = threadIdx.x;
    const int wave = tid >> 6, lane = tid & 63;
    const int b  = blockIdx.x >> 5;
    const int cg = blockIdx.x & 31;

    // ---- head: Wout convert, spread over all blocks (256 x 128 = 32768 float4s)
    if (tid < 128) {
        const int i4 = blockIdx.x * 128 + tid;   // 0..32767
        const int row = i4 >> 7;                 // 128 float4 per 512-elem row
        const int col = (i4 & 127) * 4;
        float4 v = *(const float4*)&wout[(size_t)i4*4];
        const int dcol = col ^ ((row & 7) << 3); // stays within [0,512), 4-aligned
        *(ushort4*)&woutb[(size_t)row*INNER_ + dcol] = f4bf4(v);
    }

    fl4 acc[4][2] = {};   // wave rows: wave*64 + m*16..; cols: n=0 -> u, n=1 -> g

    const int kc = (tid & 15) * 4;       // col offset (f32 elems) this thread stages
    const int rsub = tid >> 4;           // 0..31

    for (int kt = 0; kt < DIM_; kt += BK) {
        __syncthreads();
        // stage A: 512 rows x 64 k (f32 -> bf16). thread: rows rsub + p*32, cols kc..kc+3
        #pragma unroll
        for (int p = 0; p < 16; ++p) {
            const int l = p*32 + rsub;
            float4 v = *(const float4*)&x[(size_t)(b*L_ + l)*DIM_ + kt + kc];
            *(ushort4*)&As[l*LDA + kc] = f4bf4(v);
        }
        // stage Win rows (32 x 64): thread rsub = Bs row, cols kc
        {
            const int wrow = (rsub < 16) ? (cg*16 + rsub) : (INNER_ + cg*16 + (rsub-16));
            float4 v = *(const float4*)&Win[(size_t)wrow*DIM_ + kt + kc];
            *(ushort4*)&Bs[rsub*LDA + kc] = f4bf4(v);
        }
        __syncthreads();

        #pragma unroll
        for (int kh = 0; kh < 2; ++kh) {
            bf16x8 af[4], bfr[2];
            #pragma unroll
            for (int m = 0; m < 4; ++m)
                af[m] = *(const bf16x8*)&As[(wave*64 + m*16 + (lane & 15))*LDA + kh*32 + (lane >> 4)*8];
            #pragma unroll
            for (int n = 0; n < 2; ++n)
                bfr[n] = *(const bf16x8*)&Bs[(n*16 + (lane & 15))*LDA + kh*32 + (lane >> 4)*8];
            #pragma unroll
            for (int m = 0; m < 4; ++m)
                #pragma unroll
                for (int n = 0; n < 2; ++n)
                    acc[m][n] = __builtin_amdgcn_mfma_f32_16x16x32_bf16(af[m], bfr[n], acc[m][n], 0, 0, 0);
        }
    }

    __syncthreads();          // all frag reads done; reuse LDS for scan
    #pragma unroll
    for (int m = 0; m < 4; ++m)
        #pragma unroll
        for (int r = 0; r < 4; ++r) {
            const int l = wave*64 + m*16 + (lane >> 4)*4 + r;
            const int c2 = lane & 15;
            u_lds[l*17 + c2] = acc[m][0][r];
            g_lds[l*17 + c2] = acc[m][1][r];
        }
    __syncthreads();

    // scan: thread = channel c2 (0..15) x chunk j (0..31) of 16 steps
    {
        const int c2 = tid & 15;
        const int j  = tid >> 4;
        const int c  = cg*16 + c2;                 // global channel

        const float draw = 1.0f / (1.0f + __expf(-sdecay[c]));
        const float deff = fmaxf(draw, 1e-6f);
        const float ins  = (1.0f - draw) * sscale[c];
        const float w0 = convw[c*3+0], w1 = convw[c*3+1], w2 = convw[c*3+2];

        const int l0 = j*16;
        float um1 = (l0 >= 1) ? u_lds[(l0-1)*17 + c2] : 0.f;
        float um2 = (l0 >= 2) ? u_lds[(l0-2)*17 + c2] : 0.f;

        float sloc[16];
        float s = 0.f;
        #pragma unroll
        for (int i = 0; i < 16; ++i) {
            const float u = u_lds[(l0+i)*17 + c2];
            const float uc = fmaf(w2, u, fmaf(w1, um1, w0*um2));
            um2 = um1; um1 = u;
            s = fmaf(deff, s, ins*uc);
            sloc[i] = s;
        }
        carry[j*16 + c2] = s;
        __syncthreads();
        const float dp16 = __powf(deff, 16.0f);
        float s0 = 0.f;
        for (int i = 0; i < j; ++i) s0 = fmaf(s0, dp16, carry[i*16 + c2]);

        float pw = 1.0f;
        #pragma unroll
        for (int i = 0; i < 16; ++i) {
            pw *= deff;
            const float sv   = fmaf(s0, pw, sloc[i]);
            const float gate = 1.0f / (1.0f + __expf(-g_lds[(l0+i)*17 + c2]));
            // swizzled store: l = l0+i, (l&7) == (i&7) since l0 is a multiple of 16
            yb[(size_t)(b*L_ + l0 + i)*INNER_ + (c ^ ((i & 7) << 3))] = f2bf(sv * gate);
        }
    }
}

// ---------------------------------------------------------------- K2: gemm2 + fused RMSNorm
// 256 blocks x 16 rows; full 256 output cols per block; K = 512, BK = 64.
// Staging is a linear copy of the pre-swizzled buffers; fragment reads apply
// the XOR -> conflict-free. (Byte-identical to round 9.)
__global__ __launch_bounds__(512) void p3_gemm2(
    const unsigned short* __restrict__ yb,
    const unsigned short* __restrict__ woutb,
    const float* __restrict__ normw,
    float* __restrict__ out)
{
    __shared__ __align__(16) char smem[36*1024];
    unsigned short* As2 = (unsigned short*)smem;          // [16][64]
    unsigned short* Bs2 = (unsigned short*)(smem + 2048); // [256][64]
    float* ssp = (float*)(smem + 2048 + 32768);           // [16][8]
    const int tid  = threadIdx.x;
    const int wave = tid >> 6, lane = tid & 63;
    const int r15 = lane & 15, q = lane >> 4;
    const int row0 = blockIdx.x * 16;
    const int wc   = wave * 32;
    const int sa   = (r15 & 7) << 3;                      // read-side swizzle
    fl4 acc[2] = {};
    for (int kt = 0; kt < INNER_; kt += 64) {
        __syncthreads();
        for (int ch = wave; ch < 34; ch += 8) {
            const int ke = (lane & 7) * 8;
            if (ch < 2)
                gl_lds16(yb    + (size_t)(row0 + ch*8 + (lane >> 3))*INNER_ + kt + ke,
                         (char*)As2 + ch*1024);
            else
                gl_lds16(woutb + (size_t)((ch-2)*8 + (lane >> 3))*INNER_ + kt + ke,
                         (char*)Bs2 + (ch-2)*1024);
        }
        __syncthreads();
        #pragma unroll
        for (int kh = 0; kh < 2; ++kh) {
            bf16x8 a = *(const bf16x8*)&As2[r15*64 + ((kh*32 + q*8) ^ sa)];
            #pragma unroll
            for (int n = 0; n < 2; ++n) {
                bf16x8 b = *(const bf16x8*)&Bs2[(wc + n*16 + r15)*64 + ((kh*32 + q*8) ^ sa)];
                acc[n] = __builtin_amdgcn_mfma_f32_16x16x32_bf16(a, b, acc[n], 0, 0, 0);
            }
        }
    }
    float t[4];
    #pragma unroll
    for (int qq = 0; qq < 4; ++qq) {
        float s = 0.f;
        #pragma unroll
        for (int n = 0; n < 2; ++n) { const float v = acc[n][qq]; s = fmaf(v, v, s); }
        s += __shfl_xor(s, 1, 64); s += __shfl_xor(s, 2, 64);
        s += __shfl_xor(s, 4, 64); s += __shfl_xor(s, 8, 64);
        t[qq] = s;
    }
    if (r15 == 0) {
        #pragma unroll
        for (int qq = 0; qq < 4; ++qq)
            ssp[(q*4 + qq)*8 + wave] = t[qq];
    }
    __syncthreads();
    #pragma unroll
    for (int qq = 0; qq < 4; ++qq) {
        const int rl = q*4 + qq;
        float ss = 0.f;
        #pragma unroll
        for (int w = 0; w < 8; ++w) ss += ssp[rl*8 + w];
        const float rf = rsqrtf(ss * (1.0f/DIM_) + 1e-6f);
        #pragma unroll
        for (int n = 0; n < 2; ++n) {
            const int col = wc + n*16 + r15;
            out[(size_t)(row0 + rl)*DIM_ + col] = acc[n][qq] * rf * normw[col];
        }
    }
}

// ---------------------------------------------------------------- launch
extern "C" void kernel_launch(void* const* d_in, const int* in_sizes, int n_in,
                              void* d_out, int out_size, void* d_ws, size_t ws_size,
                              hipStream_t stream)
{
    const float* x      = (const float*)d_in[0];
    const float* Win    = (const float*)d_in[1];
    const float* convw  = (const float*)d_in[2];
    const float* sdecay = (const float*)d_in[3];
    const float* sscale = (const float*)d_in[4];
    const float* Wout   = (const float*)d_in[5];
    const float* normw  = (const float*)d_in[6];
    float* out = (float*)d_out;

    char* ws = (char*)d_ws;
    unsigned short* woutb = (unsigned short*)(ws);            // 0.25 MB
    unsigned short* yb    = (unsigned short*)(ws + (1u<<20)); // 4 MB

    p1_fused<<<256, 512, 0, stream>>>(x, Win, convw, sdecay, sscale, Wout, woutb, yb);
    p3_gemm2<<<256, 512, 0, stream>>>(yb, woutb, normw, out);
}